// Round 4
// baseline (276.889 us; speedup 1.0000x reference)
//
#include <hip/hip_runtime.h>
#include <hip/hip_bf16.h>

#define BS 8
#define NH 4
#define NSEQ 2048
#define FIN 64
#define FOUT 32
#define BHH (BS*NH)
#define NBINS 8192
#define LOG2E 1.44269504088896340736f

typedef float f32x4 __attribute__((ext_vector_type(4)));

// ---- small scratch in d_ws (float offsets) ----
#define WSS_SE    0
#define WSS_DE    (WSS_SE + BHH*NSEQ)
#define WSS_INVL  (WSS_DE + BHH*NSEQ)            // [BHH][NSEQ] 1/denominator per row
#define WSS_TOTAL (WSS_INVL + BHH*NSEQ)          // = 196608 floats = 786 KB

// ---- big scratch in tail of d_out's attn region (float offsets) ----
#define BIG_HP    0                               // [BHH][NSEQ][FOUT]
#define BIG_SUFP  (BIG_HP + BHH*NSEQ*FOUT)        // [BHH][NSEQ+1][FOUT] vector suffix sums of 2^d'*hp
#define BIG_PREN  (BIG_SUFP + BHH*(NSEQ+1)*FOUT)  // [BHH][NSEQ+1][FOUT] vector prefix sums of 2^(.2d')*hp
#define BIG_TOTAL (BIG_PREN + BHH*(NSEQ+1)*FOUT)  // = 6,293,504 floats (25 MB) << attn (134M floats)

// K1: h_prime = h @ w per head; s = hp.a_src, d = hp.a_dst (scaled by log2 e)
__global__ __launch_bounds__(256) void k1_proj(
    const float* __restrict__ h, const float* __restrict__ w,
    const float* __restrict__ asrc, const float* __restrict__ adst,
    float* __restrict__ ws, float* __restrict__ big)
{
    __shared__ float hl[64*65];
    const int b  = blockIdx.x >> 5;
    const int i0 = (blockIdx.x & 31) * 64;
    const int tid = threadIdx.x;
    const float* hsrc = h + ((size_t)b*NSEQ + i0)*FIN;
    for (int x = tid; x < 64*64; x += 256) hl[(x>>6)*65 + (x&63)] = hsrc[x];
    __syncthreads();
    const int head = __builtin_amdgcn_readfirstlane(tid >> 6);  // wave == head
    const int r = tid & 63;
    const int i = i0 + r;
    float acc[FOUT];
#pragma unroll
    for (int o=0;o<FOUT;o++) acc[o]=0.f;
    const float* wh = w + head*FIN*FOUT;
    for (int f=0; f<FIN; f++) {
        const float hv = hl[r*65+f];
#pragma unroll
        for (int o=0;o<FOUT;o++) acc[o] += hv * wh[f*FOUT+o];
    }
    const float* as = asrc + head*FOUT;
    const float* ad = adst + head*FOUT;
    float s=0.f, d=0.f;
#pragma unroll
    for (int o=0;o<FOUT;o++){ s += acc[o]*as[o]; d += acc[o]*ad[o]; }
    const int bh = b*NH + head;
    float* hp = big + BIG_HP + ((size_t)bh*NSEQ + i)*FOUT;
#pragma unroll
    for (int o=0;o<FOUT;o+=4) { f32x4 v = {acc[o],acc[o+1],acc[o+2],acc[o+3]}; *(f32x4*)(hp+o)=v; }
    ws[WSS_SE + bh*NSEQ + i] = s * LOG2E;
    ws[WSS_DE + bh*NSEQ + i] = d * LOG2E;
}

// K2 (fused): counting-sort d'; vector suffix/prefix scans (global), scalar scans (LDS);
// per-row binary search -> inv (WSS_INVL) AND output rows. One block per (b,h).
__global__ __launch_bounds__(1024) void k2_fused(
    float* __restrict__ ws, float* __restrict__ big,
    const float* __restrict__ bvec, float* __restrict__ outp)
{
    __shared__ float key[NSEQ];
    __shared__ int   sidx[NSEQ];
    __shared__ int   hist[NBINS];        // reused: hist[i] = k per row after sort
    __shared__ float sufps[NSEQ+1];
    __shared__ float prens[NSEQ+1];
    __shared__ int   wtot[16];
    __shared__ float rmin[16], rmax[16];
    __shared__ float sMin, sInvW;
    __shared__ float totP[16][34];
    __shared__ float totN[16][34];
    const int bh = blockIdx.x;
    const int tid = threadIdx.x;
    const int wv = tid >> 6, lane = tid & 63;

    // ---- Phase A: counting sort of d' ----
    const float x0 = ws[WSS_DE + bh*NSEQ + tid];
    const float x1 = ws[WSS_DE + bh*NSEQ + tid + 1024];
    float mn = fminf(x0,x1), mx = fmaxf(x0,x1);
#pragma unroll
    for (int off=32; off; off>>=1) {
        mn = fminf(mn, __shfl_xor(mn, off));
        mx = fmaxf(mx, __shfl_xor(mx, off));
    }
    if (lane==0){ rmin[wv]=mn; rmax[wv]=mx; }
    for (int b=tid; b<NBINS; b+=1024) hist[b]=0;
    __syncthreads();
    if (tid==0){
        float a=rmin[0], b2=rmax[0];
        for (int k=1;k<16;k++){ a=fminf(a,rmin[k]); b2=fmaxf(b2,rmax[k]); }
        sMin = a;
        sInvW = (float)NBINS / (b2 - a + 1e-6f);
    }
    __syncthreads();
    const float smin = sMin, sinv = sInvW;
    int b0 = (int)((x0 - smin)*sinv); b0 = b0 > NBINS-1 ? NBINS-1 : (b0 < 0 ? 0 : b0);
    int b1 = (int)((x1 - smin)*sinv); b1 = b1 > NBINS-1 ? NBINS-1 : (b1 < 0 ? 0 : b1);
    atomicAdd(&hist[b0],1); atomicAdd(&hist[b1],1);
    __syncthreads();
    int loc[8]; int tsum=0;
#pragma unroll
    for (int k=0;k<8;k++){ loc[k]=tsum; tsum += hist[tid*8+k]; }
    int inc = tsum;
#pragma unroll
    for (int off=1; off<64; off<<=1){ int v=__shfl_up(inc,off); if (lane>=off) inc+=v; }
    if (lane==63) wtot[wv]=inc;
    const int laneex = inc - tsum;
    __syncthreads();
    if (tid==0){ int a=0; for (int k=0;k<16;k++){ int v=wtot[k]; wtot[k]=a; a+=v; } }
    __syncthreads();
    const int base = wtot[wv] + laneex;
#pragma unroll
    for (int k=0;k<8;k++) hist[tid*8+k] = base + loc[k];
    __syncthreads();
    {
        int p0 = atomicAdd(&hist[b0],1); key[p0]=x0; sidx[p0]=tid;
        int p1 = atomicAdd(&hist[b1],1); key[p1]=x1; sidx[p1]=tid+1024;
    }
    __syncthreads();

    // ---- Phase B: chunked scans (16 waves x 128 ranks) ----
    const int start = wv*128, end = start+128;
    const float* hpb = big + BIG_HP + (size_t)bh*NSEQ*FOUT;
    float aP=0.f, aN=0.f;
#pragma unroll 4
    for (int r=start; r<end; r++) {
        const float dk = key[r];
        const float wP = __builtin_amdgcn_exp2f(dk);
        const float wN = __builtin_amdgcn_exp2f(0.2f*dk);
        if (lane < FOUT) {
            const float v = hpb[sidx[r]*FOUT + lane];
            aP += wP*v; aN += wN*v;
        } else if (lane == FOUT) { aP += wP; aN += wN; }
    }
    if (lane <= FOUT) { totP[wv][lane] = aP; totN[wv][lane] = aN; }
    __syncthreads();
    float offP=0.f, offN=0.f;
    if (lane <= FOUT) {
#pragma unroll
        for (int c=0;c<16;c++) { if (c>wv) offP += totP[c][lane]; if (c<wv) offN += totN[c][lane]; }
    }
    float acc = offP;
#pragma unroll 4
    for (int r=end-1; r>=start; r--) {
        const float wP = __builtin_amdgcn_exp2f(key[r]);
        if (lane < FOUT) {
            acc += wP * hpb[sidx[r]*FOUT + lane];
            big[BIG_SUFP + ((size_t)bh*(NSEQ+1) + r)*FOUT + lane] = acc;
        } else if (lane == FOUT) {
            acc += wP;
            sufps[r] = acc;
        }
    }
    acc = offN;
#pragma unroll 4
    for (int r=start; r<end; r++) {
        const float wN = __builtin_amdgcn_exp2f(0.2f*key[r]);
        if (lane < FOUT) {
            big[BIG_PREN + ((size_t)bh*(NSEQ+1) + r)*FOUT + lane] = acc;
            acc += wN * hpb[sidx[r]*FOUT + lane];
        } else if (lane == FOUT) {
            prens[r] = acc;
            acc += wN;
        }
    }
    if (tid < FOUT) big[BIG_SUFP + ((size_t)bh*(NSEQ+1) + NSEQ)*FOUT + tid] = 0.f;
    if (tid == 0)  sufps[NSEQ] = 0.f;
    if (wv == 15) {
        if (lane < FOUT) big[BIG_PREN + ((size_t)bh*(NSEQ+1) + NSEQ)*FOUT + lane] = acc;
        else if (lane == FOUT) prens[NSEQ] = acc;
    }
    __syncthreads();

    // ---- Phase C1: per-thread binary search -> k, inv ----
#pragma unroll
    for (int half = 0; half < 2; half++) {
        const int i = tid + half*1024;
        const float sp = ws[WSS_SE + bh*NSEQ + i];
        const float tau = -sp;
        int lo=0, hi=NSEQ;
        while (lo < hi) { const int mid=(lo+hi)>>1; if (key[mid] < tau) lo=mid+1; else hi=mid; }
        const float e1 = __builtin_amdgcn_exp2f(sp);
        const float e2 = __builtin_amdgcn_exp2f(0.2f*sp);
        const float l = e1*sufps[lo] + e2*prens[lo];
        ws[WSS_INVL + bh*NSEQ + i] = 1.0f / l;
        hist[i] = lo;
    }
    __syncthreads();

    // ---- Phase C2: output rows from vector tables (L2-hot, just written) ----
    const float bval = (lane < FOUT) ? bvec[lane] : 0.f;
#pragma unroll 2
    for (int r = 0; r < 128; r++) {
        const int i = wv*128 + r;
        const int k = hist[i];
        const float sp = ws[WSS_SE + bh*NSEQ + i];
        const float e1 = __builtin_amdgcn_exp2f(sp);
        const float e2 = __builtin_amdgcn_exp2f(0.2f*sp);
        const float l = e1*sufps[k] + e2*prens[k];
        if (lane < FOUT) {
            const float ov = (e1*big[BIG_SUFP + ((size_t)bh*(NSEQ+1)+k)*FOUT + lane]
                            + e2*big[BIG_PREN + ((size_t)bh*(NSEQ+1)+k)*FOUT + lane]) / l + bval;
            outp[((size_t)bh*NSEQ + i)*FOUT + lane] = ov;
        }
    }
}

// K3b v2: stream attn with ZERO transcendentals in the hot loop.
// p[i][j] = (E1[j] >= T[i]) ? A[i]*E1[j] : B[i]*E2[j]
// where E1=2^d', E2=2^(0.2d'), A=2^s'*inv, B=2^(0.2s')*inv, T=2^(-s').
// j-outer / row-inner: 2 ds_read_b128 amortized over 8 rows; 16 VALU per f32x4.
__global__ __launch_bounds__(256) void k3b_attn(
    const float* __restrict__ ws, float* __restrict__ attn)
{
    __shared__ float E1[NSEQ];
    __shared__ float E2[NSEQ];
    __shared__ float rA[32], rB[32], rT[32];
    const int bid = blockIdx.x;                   // 2048 = 8 XCDs x 256
    const int swz = (bid & 7) * 256 + (bid >> 3); // contiguous slab per XCD
    const int bh = swz >> 6;
    const int i0 = (swz & 63) * 32;
    const int tid = threadIdx.x;
    for (int x = tid; x < NSEQ; x += 256) {
        const float d = ws[WSS_DE + bh*NSEQ + x];
        E1[x] = __builtin_amdgcn_exp2f(d);
        E2[x] = __builtin_amdgcn_exp2f(0.2f*d);
    }
    if (tid < 32) {
        const float sp  = ws[WSS_SE   + bh*NSEQ + i0 + tid];
        const float inv = ws[WSS_INVL + bh*NSEQ + i0 + tid];
        rA[tid] = __builtin_amdgcn_exp2f(sp)        * inv;
        rB[tid] = __builtin_amdgcn_exp2f(0.2f*sp)   * inv;
        rT[tid] = __builtin_amdgcn_exp2f(-sp);
    }
    __syncthreads();
    const int wv = tid>>6, lane = tid&63;
    float A[8], B[8], T[8];
#pragma unroll
    for (int k=0;k<8;k++){ A[k]=rA[wv*8+k]; B[k]=rB[wv*8+k]; T[k]=rT[wv*8+k]; }
    float* rbase = attn + ((size_t)bh*NSEQ + i0 + wv*8)*NSEQ;
#pragma unroll
    for (int blk=0; blk<8; blk++) {
        const int j0 = blk*256 + lane*4;
        const f32x4 e1 = *(const f32x4*)&E1[j0];
        const f32x4 e2 = *(const f32x4*)&E2[j0];
#pragma unroll
        for (int k=0;k<8;k++) {
            f32x4 p;
            p.x = (e1.x >= T[k]) ? A[k]*e1.x : B[k]*e2.x;
            p.y = (e1.y >= T[k]) ? A[k]*e1.y : B[k]*e2.y;
            p.z = (e1.z >= T[k]) ? A[k]*e1.z : B[k]*e2.z;
            p.w = (e1.w >= T[k]) ? A[k]*e1.w : B[k]*e2.w;
            *(f32x4*)(rbase + (size_t)k*NSEQ + j0) = p;
        }
    }
}

extern "C" void kernel_launch(void* const* d_in, const int* in_sizes, int n_in,
                              void* d_out, int out_size, void* d_ws, size_t ws_size,
                              hipStream_t stream)
{
    (void)in_sizes; (void)n_in; (void)out_size; (void)ws_size;
    const float* h    = (const float*)d_in[0];
    const float* w    = (const float*)d_in[1];
    const float* asrc = (const float*)d_in[2];
    const float* adst = (const float*)d_in[3];
    const float* bvec = (const float*)d_in[4];
    float* outp = (float*)d_out;
    float* attn = outp + (size_t)BHH*NSEQ*FOUT;
    // big scratch in the TAIL of the attn region; fully read before K3b overwrites it
    float* big  = attn + (size_t)BHH*NSEQ*NSEQ - BIG_TOTAL;
    float* ws   = (float*)d_ws;   // needs 786 KB

    k1_proj  <<<BS*32,  256, 0, stream>>>(h, w, asrc, adst, ws, big);
    k2_fused <<<BHH,   1024, 0, stream>>>(ws, big, bvec, outp);
    k3b_attn <<<BHH*64, 256, 0, stream>>>(ws, attn);
}

// Round 5
// 218.138 us; speedup vs baseline: 1.2693x; 1.2693x over previous
//
#include <hip/hip_runtime.h>
#include <hip/hip_bf16.h>

#define BS 8
#define NH 4
#define NSEQ 2048
#define FIN 64
#define FOUT 32
#define CH 32
#define BHH (BS*NH)
#define NBINS 8192
#define LOG2E 1.44269504088896340736f

typedef float f32x4 __attribute__((ext_vector_type(4)));

// ---- small scratch in d_ws ----
// float region
#define WSS_SE    0
#define WSS_DE    (WSS_SE + BHH*NSEQ)
#define WSS_INVL  (WSS_DE + BHH*NSEQ)
#define WSS_KEY   (WSS_INVL + BHH*NSEQ)          // sorted d' per (b,h)
#define WSS_OFFP  (WSS_KEY + BHH*NSEQ)           // [BHH][16][CH] vector suffix offsets
#define WSS_OFFN  (WSS_OFFP + BHH*16*CH)         // [BHH][16][CH] vector prefix offsets
#define WSS_FTOT  (WSS_OFFN + BHH*16*CH)         // = 294912 floats
// int region (starts right after floats)
#define WSI_SIDX  0                               // [BHH][NSEQ] permutation
#define WSI_K     (WSI_SIDX + BHH*NSEQ)           // [BHH][NSEQ] split index per row
#define WSI_ITOT  (WSI_K + BHH*NSEQ)              // = 131072 ints  (total ws = 1.7 MB)

// ---- big scratch in tail of d_out's attn region ----
#define BIG_HP    0                               // [BHH][NSEQ][CH]
#define BIG_SUFP  (BIG_HP + BHH*NSEQ*CH)          // [BHH][NSEQ+1][CH]
#define BIG_PREN  (BIG_SUFP + BHH*(NSEQ+1)*CH)    // [BHH][NSEQ+1][CH]
#define BIG_TOTAL (BIG_PREN + BHH*(NSEQ+1)*CH)    // 25 MB << attn (537 MB)

// K1: h_prime = h @ w per head; s = hp.a_src, d = hp.a_dst (log2-scaled)
__global__ __launch_bounds__(256) void k1_proj(
    const float* __restrict__ h, const float* __restrict__ w,
    const float* __restrict__ asrc, const float* __restrict__ adst,
    float* __restrict__ ws, float* __restrict__ big)
{
    __shared__ float hl[64*65];
    const int b  = blockIdx.x >> 5;
    const int i0 = (blockIdx.x & 31) * 64;
    const int tid = threadIdx.x;
    const float* hsrc = h + ((size_t)b*NSEQ + i0)*FIN;
    for (int x = tid; x < 64*64; x += 256) hl[(x>>6)*65 + (x&63)] = hsrc[x];
    __syncthreads();
    const int head = __builtin_amdgcn_readfirstlane(tid >> 6);
    const int r = tid & 63;
    const int i = i0 + r;
    float acc[FOUT];
#pragma unroll
    for (int o=0;o<FOUT;o++) acc[o]=0.f;
    const float* wh = w + head*FIN*FOUT;
    for (int f=0; f<FIN; f++) {
        const float hv = hl[r*65+f];
#pragma unroll
        for (int o=0;o<FOUT;o++) acc[o] += hv * wh[f*FOUT+o];
    }
    const float* as = asrc + head*FOUT;
    const float* ad = adst + head*FOUT;
    float s=0.f, d=0.f;
#pragma unroll
    for (int o=0;o<FOUT;o++){ s += acc[o]*as[o]; d += acc[o]*ad[o]; }
    const int bh = b*NH + head;
    float* hp = big + BIG_HP + ((size_t)bh*NSEQ + i)*CH;
#pragma unroll
    for (int o=0;o<FOUT;o+=4) { f32x4 v = {acc[o],acc[o+1],acc[o+2],acc[o+3]}; *(f32x4*)(hp+o)=v; }
    ws[WSS_SE + bh*NSEQ + i] = s * LOG2E;
    ws[WSS_DE + bh*NSEQ + i] = d * LOG2E;
}

// K2a: counting-sort d'; ONE totals gather pass; scalar scans (LDS); per-row k + inv.
__global__ __launch_bounds__(1024) void k2a(
    float* __restrict__ ws, int* __restrict__ wsi, const float* __restrict__ big)
{
    __shared__ float key[NSEQ];
    __shared__ int   sidx[NSEQ];
    __shared__ int   hist[NBINS];
    __shared__ float sufps[NSEQ+1];
    __shared__ float prens[NSEQ+1];
    __shared__ int   wtot[16];
    __shared__ float rmin[16], rmax[16];
    __shared__ float sMin, sInvW;
    __shared__ float totP[16][34];
    __shared__ float totN[16][34];
    const int bh = blockIdx.x;
    const int tid = threadIdx.x;
    const int wv = tid >> 6, lane = tid & 63;

    // ---- sort ----
    const float x0 = ws[WSS_DE + bh*NSEQ + tid];
    const float x1 = ws[WSS_DE + bh*NSEQ + tid + 1024];
    float mn = fminf(x0,x1), mx = fmaxf(x0,x1);
#pragma unroll
    for (int off=32; off; off>>=1) {
        mn = fminf(mn, __shfl_xor(mn, off));
        mx = fmaxf(mx, __shfl_xor(mx, off));
    }
    if (lane==0){ rmin[wv]=mn; rmax[wv]=mx; }
    for (int bb=tid; bb<NBINS; bb+=1024) hist[bb]=0;
    __syncthreads();
    if (tid==0){
        float a=rmin[0], b2=rmax[0];
        for (int k=1;k<16;k++){ a=fminf(a,rmin[k]); b2=fmaxf(b2,rmax[k]); }
        sMin = a;
        sInvW = (float)NBINS / (b2 - a + 1e-6f);
    }
    __syncthreads();
    const float smin = sMin, sinv = sInvW;
    int b0 = (int)((x0 - smin)*sinv); b0 = b0 > NBINS-1 ? NBINS-1 : (b0 < 0 ? 0 : b0);
    int b1 = (int)((x1 - smin)*sinv); b1 = b1 > NBINS-1 ? NBINS-1 : (b1 < 0 ? 0 : b1);
    atomicAdd(&hist[b0],1); atomicAdd(&hist[b1],1);
    __syncthreads();
    int loc[8]; int tsum=0;
#pragma unroll
    for (int k=0;k<8;k++){ loc[k]=tsum; tsum += hist[tid*8+k]; }
    int inc = tsum;
#pragma unroll
    for (int off=1; off<64; off<<=1){ int v=__shfl_up(inc,off); if (lane>=off) inc+=v; }
    if (lane==63) wtot[wv]=inc;
    const int laneex = inc - tsum;
    __syncthreads();
    if (tid==0){ int a=0; for (int k=0;k<16;k++){ int v=wtot[k]; wtot[k]=a; a+=v; } }
    __syncthreads();
    const int base = wtot[wv] + laneex;
#pragma unroll
    for (int k=0;k<8;k++) hist[tid*8+k] = base + loc[k];
    __syncthreads();
    {
        int p0 = atomicAdd(&hist[b0],1); key[p0]=x0; sidx[p0]=tid;
        int p1 = atomicAdd(&hist[b1],1); key[p1]=x1; sidx[p1]=tid+1024;
    }
    __syncthreads();
    for (int x = tid; x < NSEQ; x += 1024) {
        ws[WSS_KEY + bh*NSEQ + x]  = key[x];
        wsi[WSI_SIDX + bh*NSEQ + x] = sidx[x];
    }

    // ---- single totals gather pass (16 waves x 128 ranks) ----
    const int start = wv*128, end = start+128;
    const float* hpb = big + BIG_HP + (size_t)bh*NSEQ*CH;
    float aP=0.f, aN=0.f;
#pragma unroll 8
    for (int r=start; r<end; r++) {
        const float dk = key[r];
        const float wP = __builtin_amdgcn_exp2f(dk);
        const float wN = __builtin_amdgcn_exp2f(0.2f*dk);
        if (lane < CH) {
            const float v = hpb[(size_t)sidx[r]*CH + lane];
            aP += wP*v; aN += wN*v;
        } else if (lane == CH) { aP += wP; aN += wN; }
    }
    if (lane <= CH) { totP[wv][lane] = aP; totN[wv][lane] = aN; }
    __syncthreads();
    float offP=0.f, offN=0.f;
    if (lane <= CH) {
#pragma unroll
        for (int c=0;c<16;c++) { if (c>wv) offP += totP[c][lane]; if (c<wv) offN += totN[c][lane]; }
    }
    // vector offsets -> ws for K2b
    if (lane < CH) {
        ws[WSS_OFFP + (bh*16 + wv)*CH + lane] = offP;
        ws[WSS_OFFN + (bh*16 + wv)*CH + lane] = offN;
    }
    // scalar scans in LDS (chunk-parallel, lane==CH only; no gathers)
    if (lane == CH) {
        float acc = offP;
        for (int r=end-1; r>=start; r--) { acc += __builtin_amdgcn_exp2f(key[r]); sufps[r] = acc; }
        acc = offN;
        for (int r=start; r<end; r++) { prens[r] = acc; acc += __builtin_amdgcn_exp2f(0.2f*key[r]); }
        if (wv == 15) prens[NSEQ] = acc;
    }
    if (tid == 0) sufps[NSEQ] = 0.f;
    __syncthreads();

    // ---- per-row binary search -> k, inv ----
#pragma unroll
    for (int half = 0; half < 2; half++) {
        const int i = tid + half*1024;
        const float sp = ws[WSS_SE + bh*NSEQ + i];
        const float tau = -sp;
        int lo=0, hi=NSEQ;
        while (lo < hi) { const int mid=(lo+hi)>>1; if (key[mid] < tau) lo=mid+1; else hi=mid; }
        const float e1 = __builtin_amdgcn_exp2f(sp);
        const float e2 = __builtin_amdgcn_exp2f(0.2f*sp);
        const float l = e1*sufps[lo] + e2*prens[lo];
        ws[WSS_INVL + bh*NSEQ + i] = 1.0f / l;
        wsi[WSI_K + bh*NSEQ + i] = lo;
    }
}

// K2b: per (bh,chunk) table build. Gather once into LDS (full-chip TLP), local scans, store.
__global__ __launch_bounds__(256) void k2b(
    const float* __restrict__ ws, const int* __restrict__ wsi, float* __restrict__ big)
{
    __shared__ float SP[128][CH];
    __shared__ float SN[128][CH];
    __shared__ float offv[2][CH];
    const int bid = blockIdx.x;
    const int bh = bid >> 4, c = bid & 15;
    const int tid = threadIdx.x, wv = tid>>6, lane = tid&63;
    if (tid < CH) {
        offv[0][tid] = ws[WSS_OFFP + (bh*16 + c)*CH + tid];
        offv[1][tid] = ws[WSS_OFFN + (bh*16 + c)*CH + tid];
    }
    const float* hpb = big + BIG_HP + (size_t)bh*NSEQ*CH;
    const int half = lane >> 5, ch = lane & 31;
#pragma unroll 4
    for (int t=0; t<16; t++) {
        const int rr = wv*32 + t*2 + half;          // 0..127
        const int r  = c*128 + rr;
        const float dk = ws[WSS_KEY + bh*NSEQ + r];
        const int  si  = wsi[WSI_SIDX + bh*NSEQ + r];
        const float v  = hpb[(size_t)si*CH + ch];
        SP[rr][ch] = __builtin_amdgcn_exp2f(dk)      * v;
        SN[rr][ch] = __builtin_amdgcn_exp2f(0.2f*dk) * v;
    }
    __syncthreads();
    const size_t tb = (size_t)bh*(NSEQ+1);
    if (wv == 0 && lane < CH) {
        float acc = offv[0][lane];
        for (int rr=127; rr>=0; rr--) {
            acc += SP[rr][lane];
            big[BIG_SUFP + (tb + c*128 + rr)*CH + lane] = acc;
        }
        if (c == 15) big[BIG_SUFP + (tb + NSEQ)*CH + lane] = 0.f;
    } else if (wv == 1 && lane < CH) {
        float acc = offv[1][lane];
        for (int rr=0; rr<128; rr++) {
            big[BIG_PREN + (tb + c*128 + rr)*CH + lane] = acc;
            acc += SN[rr][lane];
        }
        if (c == 15) big[BIG_PREN + (tb + NSEQ)*CH + lane] = acc;
    }
}

// K2c: output rows — 2 gathers per row, 512 blocks (full-chip TLP).
__global__ __launch_bounds__(256) void k2c(
    const float* __restrict__ ws, const int* __restrict__ wsi,
    const float* __restrict__ big, const float* __restrict__ bvec,
    float* __restrict__ outp)
{
    const int bid = blockIdx.x;
    const int bh = bid >> 4, q = bid & 15;
    const int tid = threadIdx.x, wv = tid>>6, lane = tid&63;
    const float bval = (lane < CH) ? bvec[lane] : 0.f;
    const size_t tb = (size_t)bh*(NSEQ+1);
#pragma unroll 4
    for (int t=0; t<32; t++) {
        const int i = q*128 + wv*32 + t;
        const float sp  = ws[WSS_SE   + bh*NSEQ + i];
        const float inv = ws[WSS_INVL + bh*NSEQ + i];
        const int   k   = wsi[WSI_K   + bh*NSEQ + i];
        const float e1 = __builtin_amdgcn_exp2f(sp);
        const float e2 = __builtin_amdgcn_exp2f(0.2f*sp);
        if (lane < CH) {
            const float S = big[BIG_SUFP + (tb + k)*CH + lane];
            const float P = big[BIG_PREN + (tb + k)*CH + lane];
            outp[((size_t)bh*NSEQ + i)*CH + lane] = (e1*S + e2*P)*inv + bval;
        }
    }
}

// K3b: stream attn, zero transcendentals in hot loop (R4 version).
__global__ __launch_bounds__(256) void k3b_attn(
    const float* __restrict__ ws, float* __restrict__ attn)
{
    __shared__ float E1[NSEQ];
    __shared__ float E2[NSEQ];
    __shared__ float rA[32], rB[32], rT[32];
    const int bid = blockIdx.x;                   // 2048 = 8 XCDs x 256
    const int swz = (bid & 7) * 256 + (bid >> 3);
    const int bh = swz >> 6;
    const int i0 = (swz & 63) * 32;
    const int tid = threadIdx.x;
    for (int x = tid; x < NSEQ; x += 256) {
        const float d = ws[WSS_DE + bh*NSEQ + x];
        E1[x] = __builtin_amdgcn_exp2f(d);
        E2[x] = __builtin_amdgcn_exp2f(0.2f*d);
    }
    if (tid < 32) {
        const float sp  = ws[WSS_SE   + bh*NSEQ + i0 + tid];
        const float inv = ws[WSS_INVL + bh*NSEQ + i0 + tid];
        rA[tid] = __builtin_amdgcn_exp2f(sp)      * inv;
        rB[tid] = __builtin_amdgcn_exp2f(0.2f*sp) * inv;
        rT[tid] = __builtin_amdgcn_exp2f(-sp);
    }
    __syncthreads();
    const int wv = tid>>6, lane = tid&63;
    float A[8], B[8], T[8];
#pragma unroll
    for (int k=0;k<8;k++){ A[k]=rA[wv*8+k]; B[k]=rB[wv*8+k]; T[k]=rT[wv*8+k]; }
    float* rbase = attn + ((size_t)bh*NSEQ + i0 + wv*8)*NSEQ;
#pragma unroll
    for (int blk=0; blk<8; blk++) {
        const int j0 = blk*256 + lane*4;
        const f32x4 e1 = *(const f32x4*)&E1[j0];
        const f32x4 e2 = *(const f32x4*)&E2[j0];
#pragma unroll
        for (int k=0;k<8;k++) {
            f32x4 p;
            p.x = (e1.x >= T[k]) ? A[k]*e1.x : B[k]*e2.x;
            p.y = (e1.y >= T[k]) ? A[k]*e1.y : B[k]*e2.y;
            p.z = (e1.z >= T[k]) ? A[k]*e1.z : B[k]*e2.z;
            p.w = (e1.w >= T[k]) ? A[k]*e1.w : B[k]*e2.w;
            *(f32x4*)(rbase + (size_t)k*NSEQ + j0) = p;
        }
    }
}

extern "C" void kernel_launch(void* const* d_in, const int* in_sizes, int n_in,
                              void* d_out, int out_size, void* d_ws, size_t ws_size,
                              hipStream_t stream)
{
    (void)in_sizes; (void)n_in; (void)out_size; (void)ws_size;
    const float* h    = (const float*)d_in[0];
    const float* w    = (const float*)d_in[1];
    const float* asrc = (const float*)d_in[2];
    const float* adst = (const float*)d_in[3];
    const float* bvec = (const float*)d_in[4];
    float* outp = (float*)d_out;
    float* attn = outp + (size_t)BHH*NSEQ*FOUT;
    float* big  = attn + (size_t)BHH*NSEQ*NSEQ - BIG_TOTAL;  // tail of attn region
    float* ws   = (float*)d_ws;
    int*   wsi  = (int*)(ws + WSS_FTOT);

    k1_proj  <<<BS*32,   256, 0, stream>>>(h, w, asrc, adst, ws, big);
    k2a      <<<BHH,    1024, 0, stream>>>(ws, wsi, big);
    k2b      <<<BHH*16,  256, 0, stream>>>(ws, wsi, big);
    k2c      <<<BHH*16,  256, 0, stream>>>(ws, wsi, big, bvec, outp);
    k3b_attn <<<BHH*64,  256, 0, stream>>>(ws, attn);
}

// Round 6
// 159.154 us; speedup vs baseline: 1.7398x; 1.3706x over previous
//
#include <hip/hip_runtime.h>
#include <hip/hip_bf16.h>

#define BS 8
#define NH 4
#define NSEQ 2048
#define FIN 64
#define FOUT 32
#define CH 32
#define BHH (BS*NH)
#define NBINS 8192
#define LOG2E 1.44269504088896340736f

typedef float f32x4 __attribute__((ext_vector_type(4)));

// ---- small scratch in d_ws ----
// float region
#define WSS_SE    0
#define WSS_DE    (WSS_SE + BHH*NSEQ)
#define WSS_INVL  (WSS_DE + BHH*NSEQ)
#define WSS_KEY   (WSS_INVL + BHH*NSEQ)          // sorted d' per (b,h)
#define WSS_SUFL  (WSS_KEY + BHH*NSEQ)           // [BHH][NSEQ] scalar LOCAL suffix (per 128-chunk)
#define WSS_PREL  (WSS_SUFL + BHH*NSEQ)          // [BHH][NSEQ] scalar LOCAL prefix
#define WSS_TOTP  (WSS_PREL + BHH*NSEQ)          // [BHH][16] scalar chunk totals (P)
#define WSS_TOTN  (WSS_TOTP + BHH*16)            // [BHH][16] scalar chunk totals (N)
#define WSS_VTOTP (WSS_TOTN + BHH*16)            // [BHH][16][CH] vector chunk totals (P)
#define WSS_VTOTN (WSS_VTOTP + BHH*16*CH)        // [BHH][16][CH] vector chunk totals (N)
#define WSS_FTOT  (WSS_VTOTN + BHH*16*CH)        // ~ 427K floats = 1.7 MB
// int region
#define WSI_SIDX  0                               // [BHH][NSEQ] permutation

// ---- big scratch in tail of d_out's attn region ----
#define BIG_HP    0                               // [BHH][NSEQ][CH]
#define BIG_SUFP  (BIG_HP + BHH*NSEQ*CH)          // [BHH][NSEQ][CH] LOCAL vector suffix
#define BIG_PREN  (BIG_SUFP + BHH*NSEQ*CH)        // [BHH][NSEQ][CH] LOCAL vector prefix
#define BIG_TOTAL (BIG_PREN + BHH*NSEQ*CH)        // 24 MB << attn (537 MB)

// K1: h_prime = h @ w per head; s = hp.a_src, d = hp.a_dst (log2-scaled)
__global__ __launch_bounds__(256) void k1_proj(
    const float* __restrict__ h, const float* __restrict__ w,
    const float* __restrict__ asrc, const float* __restrict__ adst,
    float* __restrict__ ws, float* __restrict__ big)
{
    __shared__ float hl[64*65];
    const int b  = blockIdx.x >> 5;
    const int i0 = (blockIdx.x & 31) * 64;
    const int tid = threadIdx.x;
    const float* hsrc = h + ((size_t)b*NSEQ + i0)*FIN;
    for (int x = tid; x < 64*64; x += 256) hl[(x>>6)*65 + (x&63)] = hsrc[x];
    __syncthreads();
    const int head = __builtin_amdgcn_readfirstlane(tid >> 6);
    const int r = tid & 63;
    const int i = i0 + r;
    float acc[FOUT];
#pragma unroll
    for (int o=0;o<FOUT;o++) acc[o]=0.f;
    const float* wh = w + head*FIN*FOUT;
    for (int f=0; f<FIN; f++) {
        const float hv = hl[r*65+f];
#pragma unroll
        for (int o=0;o<FOUT;o++) acc[o] += hv * wh[f*FOUT+o];
    }
    const float* as = asrc + head*FOUT;
    const float* ad = adst + head*FOUT;
    float s=0.f, d=0.f;
#pragma unroll
    for (int o=0;o<FOUT;o++){ s += acc[o]*as[o]; d += acc[o]*ad[o]; }
    const int bh = b*NH + head;
    float* hp = big + BIG_HP + ((size_t)bh*NSEQ + i)*CH;
#pragma unroll
    for (int o=0;o<FOUT;o+=4) { f32x4 v = {acc[o],acc[o+1],acc[o+2],acc[o+3]}; *(f32x4*)(hp+o)=v; }
    ws[WSS_SE + bh*NSEQ + i] = s * LOG2E;
    ws[WSS_DE + bh*NSEQ + i] = d * LOG2E;
}

// KH: counting sort ONLY (fixed-range bins, LDS histogram+scan, scatter to global).
__global__ __launch_bounds__(1024) void kh_sort(
    float* __restrict__ ws, int* __restrict__ wsi)
{
    __shared__ int hist[NBINS];
    __shared__ int wtot[16];
    const int bh = blockIdx.x;
    const int tid = threadIdx.x;
    const int wv = tid >> 6, lane = tid & 63;
    const float x0 = ws[WSS_DE + bh*NSEQ + tid];
    const float x1 = ws[WSS_DE + bh*NSEQ + tid + 1024];
    for (int bb=tid; bb<NBINS; bb+=1024) hist[bb]=0;
    __syncthreads();
    // fixed range ±8 (12 sigma of d'); clamp is monotone -> order preserved
    int b0 = (int)((x0 + 8.0f)*512.0f); b0 = b0 > NBINS-1 ? NBINS-1 : (b0 < 0 ? 0 : b0);
    int b1 = (int)((x1 + 8.0f)*512.0f); b1 = b1 > NBINS-1 ? NBINS-1 : (b1 < 0 ? 0 : b1);
    atomicAdd(&hist[b0],1); atomicAdd(&hist[b1],1);
    __syncthreads();
    int loc[8]; int tsum=0;
#pragma unroll
    for (int k=0;k<8;k++){ loc[k]=tsum; tsum += hist[tid*8+k]; }
    int inc = tsum;
#pragma unroll
    for (int off=1; off<64; off<<=1){ int v=__shfl_up(inc,off); if (lane>=off) inc+=v; }
    if (lane==63) wtot[wv]=inc;
    const int laneex = inc - tsum;
    __syncthreads();
    if (tid==0){ int a=0; for (int k=0;k<16;k++){ int v=wtot[k]; wtot[k]=a; a+=v; } }
    __syncthreads();
    const int base = wtot[wv] + laneex;
#pragma unroll
    for (int k=0;k<8;k++) hist[tid*8+k] = base + loc[k];
    __syncthreads();
    {
        int p0 = atomicAdd(&hist[b0],1);
        ws[WSS_KEY + bh*NSEQ + p0] = x0; wsi[WSI_SIDX + bh*NSEQ + p0] = tid;
        int p1 = atomicAdd(&hist[b1],1);
        ws[WSS_KEY + bh*NSEQ + p1] = x1; wsi[WSI_SIDX + bh*NSEQ + p1] = tid + 1024;
    }
}

// K2b: per (bh, 128-rank chunk): gather hp once, LOCAL scans (vector+scalar), chunk totals.
__global__ __launch_bounds__(256) void k2b(
    float* __restrict__ ws, const int* __restrict__ wsi, float* __restrict__ big)
{
    __shared__ float kk[128];
    __shared__ int   si[128];
    __shared__ float SP[128][CH];
    __shared__ float SN[128][CH];
    const int bid = blockIdx.x;
    const int bh = bid >> 4, c = bid & 15;
    const int tid = threadIdx.x, wv = tid>>6, lane = tid&63;
    if (tid < 128) {
        kk[tid] = ws[WSS_KEY + bh*NSEQ + c*128 + tid];
        si[tid] = wsi[WSI_SIDX + bh*NSEQ + c*128 + tid];
    }
    __syncthreads();
    const float* hpb = big + BIG_HP + (size_t)bh*NSEQ*CH;
    const int half = lane >> 5, ch = lane & 31;
#pragma unroll 4
    for (int t=0; t<16; t++) {
        const int rr = wv*32 + t*2 + half;
        const float dk = kk[rr];
        const float v  = hpb[(size_t)si[rr]*CH + ch];
        SP[rr][ch] = __builtin_amdgcn_exp2f(dk)      * v;
        SN[rr][ch] = __builtin_amdgcn_exp2f(0.2f*dk) * v;
    }
    __syncthreads();
    const size_t tb = (size_t)bh*NSEQ + c*128;
    if (wv == 0 && lane < CH) {                 // vector local suffix
        float acc = 0.f;
        for (int rr=127; rr>=0; rr--) {
            acc += SP[rr][lane];
            big[BIG_SUFP + (tb + rr)*CH + lane] = acc;
        }
        ws[WSS_VTOTP + (bh*16 + c)*CH + lane] = acc;
    } else if (wv == 1 && lane < CH) {          // vector local prefix
        float acc = 0.f;
        for (int rr=0; rr<128; rr++) {
            big[BIG_PREN + (tb + rr)*CH + lane] = acc;
            acc += SN[rr][lane];
        }
        ws[WSS_VTOTN + (bh*16 + c)*CH + lane] = acc;
    } else if (wv == 2 && lane == 0) {          // scalar local suffix
        float acc = 0.f;
        for (int rr=127; rr>=0; rr--) {
            acc += __builtin_amdgcn_exp2f(kk[rr]);
            ws[WSS_SUFL + tb + rr] = acc;
        }
        ws[WSS_TOTP + bh*16 + c] = acc;
    } else if (wv == 3 && lane == 0) {          // scalar local prefix
        float acc = 0.f;
        for (int rr=0; rr<128; rr++) {
            ws[WSS_PREL + tb + rr] = acc;
            acc += __builtin_amdgcn_exp2f(0.2f*kk[rr]);
        }
        ws[WSS_TOTN + bh*16 + c] = acc;
    }
}

// K2c: per (bh, 128-row chunk): offsets in-block; binsearch -> l, inv; output rows.
__global__ __launch_bounds__(256) void k2c(
    float* __restrict__ ws, const float* __restrict__ big,
    const float* __restrict__ bvec, float* __restrict__ outp)
{
    __shared__ float keys[NSEQ];
    __shared__ float sufl[NSEQ];
    __shared__ float prel[NSEQ];
    __shared__ float vofP[17][CH];
    __shared__ float vofN[17][CH];
    __shared__ float sofP[17], sofN[17];
    __shared__ int   krow[128];
    __shared__ float invrow[128], e1row[128], e2row[128];
    const int bid = blockIdx.x;
    const int bh = bid >> 4, q = bid & 15;
    const int tid = threadIdx.x, wv = tid>>6, lane = tid&63;
    for (int x = tid; x < NSEQ; x += 256) {
        keys[x] = ws[WSS_KEY  + bh*NSEQ + x];
        sufl[x] = ws[WSS_SUFL + bh*NSEQ + x];
        prel[x] = ws[WSS_PREL + bh*NSEQ + x];
    }
    if (tid < CH) {                              // vector chunk offsets
        float a = 0.f;
        for (int c=15; c>=0; c--) { vofP[c][tid] = a; a += ws[WSS_VTOTP + (bh*16+c)*CH + tid]; }
        vofP[16][tid] = 0.f;
        a = 0.f;
        for (int c=0; c<16; c++) { vofN[c][tid] = a; a += ws[WSS_VTOTN + (bh*16+c)*CH + tid]; }
        vofN[16][tid] = a;                       // grand total N
    } else if (tid == 64) {                      // scalar chunk offsets
        float a = 0.f;
        for (int c=15; c>=0; c--) { sofP[c] = a; a += ws[WSS_TOTP + bh*16 + c]; }
        sofP[16] = 0.f;
        a = 0.f;
        for (int c=0; c<16; c++) { sofN[c] = a; a += ws[WSS_TOTN + bh*16 + c]; }
        sofN[16] = a;
    }
    __syncthreads();
    if (tid < 128) {                             // binsearch + l + inv
        const int i = q*128 + tid;
        const float sp = ws[WSS_SE + bh*NSEQ + i];
        const float tau = -sp;
        int lo=0, hi=NSEQ;
        while (lo < hi) { const int mid=(lo+hi)>>1; if (keys[mid] < tau) lo=mid+1; else hi=mid; }
        const float e1 = __builtin_amdgcn_exp2f(sp);
        const float e2 = __builtin_amdgcn_exp2f(0.2f*sp);
        const float Ss = (lo==NSEQ) ? 0.f        : sufl[lo] + sofP[lo>>7];
        const float Ns = (lo==NSEQ) ? sofN[16]   : prel[lo] + sofN[lo>>7];
        const float inv = 1.0f / (e1*Ss + e2*Ns);
        ws[WSS_INVL + bh*NSEQ + i] = inv;
        krow[tid]=lo; invrow[tid]=inv; e1row[tid]=e1; e2row[tid]=e2;
    }
    __syncthreads();
    const int half = lane >> 5, ch = lane & 31;  // output rows: 4 waves x 32 rows
    const float bval = bvec[ch];
    const size_t tb = (size_t)bh*NSEQ;
#pragma unroll 4
    for (int t=0; t<16; t++) {
        const int r = wv*32 + t*2 + half;
        const int k = krow[r];
        const float S = (k==NSEQ) ? 0.f      : big[BIG_SUFP + (tb + k)*CH + ch] + vofP[k>>7][ch];
        const float N = (k==NSEQ) ? vofN[16][ch] : big[BIG_PREN + (tb + k)*CH + ch] + vofN[k>>7][ch];
        outp[(tb + q*128 + r)*CH + ch] = (e1row[r]*S + e2row[r]*N)*invrow[r] + bval;
    }
}

// K3b: stream attn, zero transcendentals in hot loop.
__global__ __launch_bounds__(256) void k3b_attn(
    const float* __restrict__ ws, float* __restrict__ attn)
{
    __shared__ float E1[NSEQ];
    __shared__ float E2[NSEQ];
    __shared__ float rA[32], rB[32], rT[32];
    const int bid = blockIdx.x;                   // 2048 = 8 XCDs x 256
    const int swz = (bid & 7) * 256 + (bid >> 3);
    const int bh = swz >> 6;
    const int i0 = (swz & 63) * 32;
    const int tid = threadIdx.x;
    for (int x = tid; x < NSEQ; x += 256) {
        const float d = ws[WSS_DE + bh*NSEQ + x];
        E1[x] = __builtin_amdgcn_exp2f(d);
        E2[x] = __builtin_amdgcn_exp2f(0.2f*d);
    }
    if (tid < 32) {
        const float sp  = ws[WSS_SE   + bh*NSEQ + i0 + tid];
        const float inv = ws[WSS_INVL + bh*NSEQ + i0 + tid];
        rA[tid] = __builtin_amdgcn_exp2f(sp)      * inv;
        rB[tid] = __builtin_amdgcn_exp2f(0.2f*sp) * inv;
        rT[tid] = __builtin_amdgcn_exp2f(-sp);
    }
    __syncthreads();
    const int wv = tid>>6, lane = tid&63;
    float A[8], B[8], T[8];
#pragma unroll
    for (int k=0;k<8;k++){ A[k]=rA[wv*8+k]; B[k]=rB[wv*8+k]; T[k]=rT[wv*8+k]; }
    float* rbase = attn + ((size_t)bh*NSEQ + i0 + wv*8)*NSEQ;
#pragma unroll
    for (int blk=0; blk<8; blk++) {
        const int j0 = blk*256 + lane*4;
        const f32x4 e1 = *(const f32x4*)&E1[j0];
        const f32x4 e2 = *(const f32x4*)&E2[j0];
#pragma unroll
        for (int k=0;k<8;k++) {
            f32x4 p;
            p.x = (e1.x >= T[k]) ? A[k]*e1.x : B[k]*e2.x;
            p.y = (e1.y >= T[k]) ? A[k]*e1.y : B[k]*e2.y;
            p.z = (e1.z >= T[k]) ? A[k]*e1.z : B[k]*e2.z;
            p.w = (e1.w >= T[k]) ? A[k]*e1.w : B[k]*e2.w;
            *(f32x4*)(rbase + (size_t)k*NSEQ + j0) = p;
        }
    }
}

extern "C" void kernel_launch(void* const* d_in, const int* in_sizes, int n_in,
                              void* d_out, int out_size, void* d_ws, size_t ws_size,
                              hipStream_t stream)
{
    (void)in_sizes; (void)n_in; (void)out_size; (void)ws_size;
    const float* h    = (const float*)d_in[0];
    const float* w    = (const float*)d_in[1];
    const float* asrc = (const float*)d_in[2];
    const float* adst = (const float*)d_in[3];
    const float* bvec = (const float*)d_in[4];
    float* outp = (float*)d_out;
    float* attn = outp + (size_t)BHH*NSEQ*FOUT;
    float* big  = attn + (size_t)BHH*NSEQ*NSEQ - BIG_TOTAL;  // tail of attn region
    float* ws   = (float*)d_ws;
    int*   wsi  = (int*)(ws + WSS_FTOT);

    k1_proj  <<<BS*32,   256, 0, stream>>>(h, w, asrc, adst, ws, big);
    kh_sort  <<<BHH,    1024, 0, stream>>>(ws, wsi);
    k2b      <<<BHH*16,  256, 0, stream>>>(ws, wsi, big);
    k2c      <<<BHH*16,  256, 0, stream>>>(ws, big, bvec, outp);
    k3b_attn <<<BHH*64,  256, 0, stream>>>(ws, attn);
}